// Round 2
// baseline (536.332 us; speedup 1.0000x reference)
//
#include <hip/hip_runtime.h>
#include <hip/hip_bf16.h>
#include <cstdint>
#include <cstddef>

// ---- problem constants ----
#define NH 8
#define DMODEL 512
#define DHEAD 64
#define BB 2
#define SEQ 2048

typedef __bf16 bf16x8 __attribute__((ext_vector_type(8)));
typedef float f32x4 __attribute__((ext_vector_type(4)));
typedef unsigned short u16;
typedef unsigned int u32;

__device__ __forceinline__ float bf2f(u16 u) {
  return __uint_as_float(((u32)u) << 16);
}
__device__ __forceinline__ u16 f2bf(float f) {
  u32 x = __float_as_uint(f);
  x += 0x7fffu + ((x >> 16) & 1u);
  return (u16)(x >> 16);
}
__device__ __forceinline__ u32 pk2(float lo, float hi) {
  return (u32)f2bf(lo) | ((u32)f2bf(hi) << 16);
}

// ============ prep: W transposes + X f32->bf16 + mask bits ===========
// blockIdx.x ranges:
//   [0,256)        : transpose 4 weight matrices (64 tiles each)
//   [256,3328)     : convert q,k,v f32 -> bf16 (1024 blocks each)
//   [3328,4352)    : mask int32 -> bitmask (32 ints / thread)
__global__ __launch_bounds__(256) void prep(
    const float* Wq, const float* Wk, const float* Wv, const float* Wo,
    u16* wtq, u16* wtk, u16* wtv, u16* wto,
    const float* xq, const float* xk, const float* xv,
    u16* Xq, u16* Xk, u16* Xv,
    const int* __restrict__ mask, u32* __restrict__ mbits) {
  __shared__ u16 t[64][72];
  int bid = blockIdx.x, tid = threadIdx.x;
  if (bid < 256) {
    const float* srcs[4] = {Wq, Wk, Wv, Wo};
    u16* dsts[4] = {wtq, wtk, wtv, wto};
    int z = bid >> 6, tile = bid & 63;
    int r0 = (tile >> 3) * 64, c0 = (tile & 7) * 64;
    const float* src = srcs[z] + (size_t)r0 * DMODEL + c0;
    u16* dst = dsts[z] + (size_t)c0 * DMODEL + r0;
#pragma unroll
    for (int p = 0; p < 4; ++p) {
      int c = tid + p * 256;
      int row = c >> 4, cc = (c & 15) * 4;
      float4 f = *(const float4*)(src + (size_t)row * DMODEL + cc);
      t[row][cc + 0] = f2bf(f.x); t[row][cc + 1] = f2bf(f.y);
      t[row][cc + 2] = f2bf(f.z); t[row][cc + 3] = f2bf(f.w);
    }
    __syncthreads();
#pragma unroll
    for (int p = 0; p < 2; ++p) {
      int c = tid + p * 256;
      int n = c >> 3, kc = (c & 7) * 8;
      uint4 w;
      w.x = (u32)t[kc + 0][n] | ((u32)t[kc + 1][n] << 16);
      w.y = (u32)t[kc + 2][n] | ((u32)t[kc + 3][n] << 16);
      w.z = (u32)t[kc + 4][n] | ((u32)t[kc + 5][n] << 16);
      w.w = (u32)t[kc + 6][n] | ((u32)t[kc + 7][n] << 16);
      *(uint4*)(dst + (size_t)n * DMODEL + kc) = w;
    }
  } else if (bid < 3328) {
    int id = bid - 256;
    const float* src = (id < 1024) ? xq : (id < 2048) ? xk : xv;
    u16* dst = (id < 1024) ? Xq : (id < 2048) ? Xk : Xv;
    size_t off = (size_t)(id & 1023) * 2048 + (size_t)tid * 8;
    float4 f0 = *(const float4*)(src + off);
    float4 f1 = *(const float4*)(src + off + 4);
    uint4 w = make_uint4(pk2(f0.x, f0.y), pk2(f0.z, f0.w),
                         pk2(f1.x, f1.y), pk2(f1.z, f1.w));
    *(uint4*)(dst + off) = w;
  } else {
    size_t w0 = (size_t)(bid - 3328) * 256 + tid;   // output word index
    const int* mp = mask + w0 * 32;
    u32 bits = 0;
#pragma unroll
    for (int c = 0; c < 8; ++c) {
      uint4 v = *(const uint4*)(mp + c * 4);
      bits |= (v.x != 0 ? 1u : 0u) << (c * 4 + 0);
      bits |= (v.y != 0 ? 1u : 0u) << (c * 4 + 1);
      bits |= (v.z != 0 ? 1u : 0u) << (c * 4 + 2);
      bits |= (v.w != 0 ? 1u : 0u) << (c * 4 + 3);
    }
    mbits[w0] = bits;
  }
}

// ============ V' bf16 [B*L][512] -> Vt[(b*8+h)*64+d][L] ============
__global__ __launch_bounds__(256) void transpose_v(const u16* Vp, u16* Vt) {
  __shared__ u16 t[64][72];
  int hb2 = blockIdx.y;               // b*8 + h
  int b = hb2 >> 3, h = hb2 & 7;
  int kp0 = blockIdx.x * 64;
  const u16* src = Vp + ((size_t)(b * SEQ + kp0)) * DMODEL + h * DHEAD;
  u16* dst = Vt + ((size_t)hb2 * DHEAD) * SEQ + kp0;
  int tid = threadIdx.x;
#pragma unroll
  for (int p = 0; p < 2; ++p) {
    int c = tid + p * 256;
    int row = c >> 3, cc = (c & 7) * 8;
    uint4 w = *(const uint4*)(src + (size_t)row * DMODEL + cc);
    t[row][cc + 0] = (u16)(w.x);  t[row][cc + 1] = (u16)(w.x >> 16);
    t[row][cc + 2] = (u16)(w.y);  t[row][cc + 3] = (u16)(w.y >> 16);
    t[row][cc + 4] = (u16)(w.z);  t[row][cc + 5] = (u16)(w.z >> 16);
    t[row][cc + 6] = (u16)(w.w);  t[row][cc + 7] = (u16)(w.w >> 16);
  }
  __syncthreads();
#pragma unroll
  for (int p = 0; p < 2; ++p) {
    int c = tid + p * 256;
    int n = c >> 3, kc = (c & 7) * 8;
    uint4 w;
    w.x = (u32)t[kc + 0][n] | ((u32)t[kc + 1][n] << 16);
    w.y = (u32)t[kc + 2][n] | ((u32)t[kc + 3][n] << 16);
    w.z = (u32)t[kc + 4][n] | ((u32)t[kc + 5][n] << 16);
    w.w = (u32)t[kc + 6][n] | ((u32)t[kc + 7][n] << 16);
    *(uint4*)(dst + (size_t)n * SEQ + kc) = w;
  }
}

// ======================= 128x128 MFMA GEMM ==========================
// Y[4096][512] = X[4096][512] @ W[512][512] (+bias (+resid))
// bf16 X. Double-buffered LDS + async-split staging: issue global loads
// for kt+1 before the ds_read+MFMA of kt, commit after. One barrier/kt.
template <bool YF32>
__device__ __forceinline__ void gemm_body(const u16* __restrict__ X,
                                          const u16* __restrict__ Wt,
                                          const float* __restrict__ bias,
                                          const float* __restrict__ resid,
                                          void* Yv) {
  __shared__ __align__(16) u16 aL[2][4 * 128 * 8];
  __shared__ __align__(16) u16 bL[2][4 * 128 * 8];
  int tid = threadIdx.x;
  int m0 = blockIdx.x * 128, n0 = blockIdx.y * 128;
  int wave = tid >> 6, lane = tid & 63;
  int lane16 = lane & 15, quad = lane >> 4;
  int wrow = (wave >> 1) * 64, wcol = (wave & 1) * 64;
  int row0 = tid >> 2, kq0 = tid & 3;    // p=1 is row0+64, same kq
  const u16* Abase = X + (size_t)m0 * DMODEL;
  const u16* Bbase = Wt + (size_t)n0 * DMODEL;
  uint4 ra0, ra1, rb0, rb1;
  auto issue = [&](int kt) {
    int k0 = kt * 32;
    const u16* ap = Abase + (size_t)row0 * DMODEL + k0 + kq0 * 8;
    const u16* bp = Bbase + (size_t)row0 * DMODEL + k0 + kq0 * 8;
    ra0 = *(const uint4*)(ap);
    rb0 = *(const uint4*)(bp);
    ra1 = *(const uint4*)(ap + (size_t)64 * DMODEL);
    rb1 = *(const uint4*)(bp + (size_t)64 * DMODEL);
  };
  auto commit = [&](int b) {
    *(uint4*)(aL[b] + (((kq0 * 128 + row0) ^ kq0) * 8)) = ra0;
    *(uint4*)(bL[b] + (((kq0 * 128 + row0) ^ kq0) * 8)) = rb0;
    *(uint4*)(aL[b] + (((kq0 * 128 + row0 + 64) ^ kq0) * 8)) = ra1;
    *(uint4*)(bL[b] + (((kq0 * 128 + row0 + 64) ^ kq0) * 8)) = rb1;
  };
  f32x4 acc[4][4] = {};
  issue(0);
  commit(0);
  __syncthreads();
  for (int kt = 0; kt < 16; ++kt) {
    if (kt < 15) issue(kt + 1);        // loads in flight across compute
    int b = kt & 1;
    bf16x8 aF[4], bF[4];
#pragma unroll
    for (int t = 0; t < 4; ++t) {
      aF[t] = *(const bf16x8*)(aL[b] + (((quad * 128 + wrow + t * 16 + lane16) ^ quad) * 8));
      bF[t] = *(const bf16x8*)(bL[b] + (((quad * 128 + wcol + t * 16 + lane16) ^ quad) * 8));
    }
#pragma unroll
    for (int tm = 0; tm < 4; ++tm)
#pragma unroll
      for (int tn = 0; tn < 4; ++tn)
        acc[tm][tn] = __builtin_amdgcn_mfma_f32_16x16x32_bf16(
            aF[tm], bF[tn], acc[tm][tn], 0, 0, 0);
    if (kt < 15) commit((kt + 1) & 1); // other buffer: safe, barrier(kt-1) passed
    __syncthreads();
  }
  // epilogue: C row = quad*4 + r, col = lane16 (m89/m91 verified layout)
#pragma unroll
  for (int tm = 0; tm < 4; ++tm) {
#pragma unroll
    for (int r = 0; r < 4; ++r) {
      int mm = m0 + wrow + tm * 16 + quad * 4 + r;
#pragma unroll
      for (int tn = 0; tn < 4; ++tn) {
        int n = n0 + wcol + tn * 16 + lane16;
        float v = acc[tm][tn][r] + bias[n];
        if (YF32) {
          ((float*)Yv)[(size_t)mm * DMODEL + n] = v + resid[(size_t)mm * DMODEL + n];
        } else {
          ((u16*)Yv)[(size_t)mm * DMODEL + n] = f2bf(v);
        }
      }
    }
  }
}

__global__ __launch_bounds__(256) void qkv_gemm(
    const u16* Xq, const u16* Xk, const u16* Xv,
    const u16* wtq, const u16* wtk, const u16* wtv,
    const float* bq, const float* bk, const float* bv,
    u16* yq, u16* yk, u16* yv) {
  int z = blockIdx.z;
  const u16* X = (z == 0) ? Xq : (z == 1) ? Xk : Xv;
  const u16* Wt = (z == 0) ? wtq : (z == 1) ? wtk : wtv;
  const float* bias = (z == 0) ? bq : (z == 1) ? bk : bv;
  u16* Y = (z == 0) ? yq : (z == 1) ? yk : yv;
  gemm_body<false>(X, Wt, bias, nullptr, Y);
}

__global__ __launch_bounds__(256) void out_gemm(const u16* X, const u16* Wt,
                                                const float* bias,
                                                const float* resid, float* Y) {
  gemm_body<true>(X, Wt, bias, resid, Y);
}

// ======================= flash attention (pass A) ====================
// One block = (b,h) x 64 Q rows. Online softmax + rescaled PV. Emits Ctx
// and per-row (m, 1/l). T14 async staging: K/V tile j+1 held in regs
// across S+softmax+PV of tile j; committed to LDS after PV barrier.
__global__ __launch_bounds__(256) void attn_flash(
    const u16* __restrict__ Qp, const u16* __restrict__ Kp,
    const u16* __restrict__ Vt, const u32* __restrict__ mbits,
    float* __restrict__ stats, u16* __restrict__ Ctx) {
  __shared__ __align__(16) u16 kL[8 * 128 * 8];   // 16 KB (Q -> K -> P)
  __shared__ __align__(16) u16 vL[16 * 64 * 8];   // 16 KB
  int tid = threadIdx.x;
  int hb = blockIdx.y;             // h*B + b
  int h = hb >> 1, b = hb & 1;
  int q0 = blockIdx.x * 64;
  int wave = tid >> 6, lane = tid & 63;
  int lane16 = lane & 15, quad = lane >> 4;
  int qw = wave * 16;

  const u16* Qbase = Qp + ((size_t)(b * SEQ + q0)) * DMODEL + h * DHEAD;
  const u16* Kbase = Kp + ((size_t)b * SEQ) * DMODEL + h * DHEAD;
  const u16* Vbase = Vt + ((size_t)(b * 8 + h) * DHEAD) * SEQ;
  const u32* Mb = mbits + ((size_t)(b * SEQ + q0)) * (SEQ / 32);

  uint4 rk[4], rv[4];
  auto issueKV = [&](int j) {
    int kp0 = j * 128;
#pragma unroll
    for (int p = 0; p < 4; ++p) {
      int c = tid + p * 256;
      int row = c >> 3, dq = c & 7;
      rk[p] = *(const uint4*)(Kbase + (size_t)(kp0 + row) * DMODEL + dq * 8);
      int d = c >> 4, kpq = c & 15;
      rv[p] = *(const uint4*)(Vbase + (size_t)d * SEQ + kp0 + kpq * 8);
    }
  };
  auto commitKV = [&]() {
#pragma unroll
    for (int p = 0; p < 4; ++p) {
      int c = tid + p * 256;
      int row = c >> 3, dq = c & 7;
      *(uint4*)(kL + (((dq * 128 + row) ^ dq) * 8)) = rk[p];
      int d = c >> 4, kpq = c & 15;
      *(uint4*)(vL + (((kpq * 64 + d) ^ (kpq & 7)) * 8)) = rv[p];
    }
  };

  // stage Q through kL once; hoist fragments to registers
#pragma unroll
  for (int p = 0; p < 2; ++p) {
    int c = tid + p * 256;
    int row = c >> 3, kq = c & 7;
    *(uint4*)(kL + (((kq * 64 + row) ^ kq) * 8)) =
        *(const uint4*)(Qbase + (size_t)row * DMODEL + kq * 8);
  }
  __syncthreads();
  int mq = qw + lane16;
  bf16x8 a0 = *(const bf16x8*)(kL + (((quad * 64 + mq) ^ quad) * 8));
  bf16x8 a1 = *(const bf16x8*)(kL + ((((4 + quad) * 64 + mq) ^ (4 + quad)) * 8));
  issueKV(0);
  __syncthreads();                  // Q reads complete before K overwrite
  commitKV();
  __syncthreads();

  float mrow[4], lrow[4];
#pragma unroll
  for (int r = 0; r < 4; ++r) { mrow[r] = -1e30f; lrow[r] = 0.f; }
  f32x4 oacc[4] = {};
  const float scale = 1.0f / 64.0f;   // reference temperature = d_k

  for (int j = 0; j < 16; ++j) {
    int kp0 = j * 128;
    if (j < 15) issueKV(j + 1);       // in flight across S+softmax+PV
    uint4 mw[4];
#pragma unroll
    for (int r = 0; r < 4; ++r)
      mw[r] = *(const uint4*)(Mb + (size_t)(qw + quad * 4 + r) * (SEQ / 32) + (kp0 >> 5));
    f32x4 s[8] = {};
    __builtin_amdgcn_s_setprio(1);
#pragma unroll
    for (int tn = 0; tn < 8; ++tn) {
      int rowk = tn * 16 + lane16;
      bf16x8 b0 = *(const bf16x8*)(kL + (((quad * 128 + rowk) ^ quad) * 8));
      bf16x8 b1 = *(const bf16x8*)(kL + ((((4 + quad) * 128 + rowk) ^ (4 + quad)) * 8));
      s[tn] = __builtin_amdgcn_mfma_f32_16x16x32_bf16(a0, b0, s[tn], 0, 0, 0);
      s[tn] = __builtin_amdgcn_mfma_f32_16x16x32_bf16(a1, b1, s[tn], 0, 0, 0);
    }
    __builtin_amdgcn_s_setprio(0);
    float pv[4][8], cf[4];
#pragma unroll
    for (int r = 0; r < 4; ++r) {
      u32 mwv[4] = {mw[r].x, mw[r].y, mw[r].z, mw[r].w};
      float vmax = -1e30f, sv[8];
#pragma unroll
      for (int tn = 0; tn < 8; ++tn) {
        float x = s[tn][r] * scale;
        if (((mwv[tn >> 1] >> (((tn & 1) << 4) + lane16)) & 1u) == 0u) x = -1e9f;
        sv[tn] = x;
        vmax = fmaxf(vmax, x);
      }
#pragma unroll
      for (int o = 1; o < 16; o <<= 1) vmax = fmaxf(vmax, __shfl_xor(vmax, o));
      float nm = fmaxf(mrow[r], vmax);
      cf[r] = __expf(mrow[r] - nm);
      float se = 0.f;
#pragma unroll
      for (int tn = 0; tn < 8; ++tn) {
        float e = __expf(sv[tn] - nm);
        pv[r][tn] = e;
        se += e;
      }
#pragma unroll
      for (int o = 1; o < 16; o <<= 1) se += __shfl_xor(se, o);
      lrow[r] = lrow[r] * cf[r] + se;
      mrow[r] = nm;
    }
#pragma unroll
    for (int tn = 0; tn < 4; ++tn)
#pragma unroll
      for (int r = 0; r < 4; ++r) oacc[tn][r] *= cf[r];
    __syncthreads();                  // all waves done reading kL (S phase)
    // write P into kL's space; swizzle block ^ ((m>>2)&7) separates quads
#pragma unroll
    for (int r = 0; r < 4; ++r) {
      int m = qw + quad * 4 + r;
      int sw = (m >> 2) & 7;
#pragma unroll
      for (int tn = 0; tn < 8; ++tn) {
        int kpl = tn * 16 + lane16;
        kL[((((kpl >> 3) * 64 + m) ^ sw) * 8) + (kpl & 7)] = f2bf(pv[r][tn]);
      }
    }
    __syncthreads();
    __builtin_amdgcn_s_setprio(1);
#pragma unroll
    for (int ks = 0; ks < 4; ++ks) {
      int kpq = ks * 4 + quad;
      bf16x8 aF = *(const bf16x8*)(kL + (((kpq * 64 + mq) ^ ((mq >> 2) & 7)) * 8));
#pragma unroll
      for (int tn = 0; tn < 4; ++tn) {
        bf16x8 bF = *(const bf16x8*)(vL + (((kpq * 64 + tn * 16 + lane16) ^ (kpq & 7)) * 8));
        oacc[tn] = __builtin_amdgcn_mfma_f32_16x16x32_bf16(aF, bF, oacc[tn], 0, 0, 0);
      }
    }
    __builtin_amdgcn_s_setprio(0);
    __syncthreads();                  // PV reads done -> safe to overwrite
    if (j < 15) {
      commitKV();
      __syncthreads();                // staged tile visible for next S
    }
  }
  float rl[4];
#pragma unroll
  for (int r = 0; r < 4; ++r) rl[r] = 1.0f / lrow[r];
#pragma unroll
  for (int tn = 0; tn < 4; ++tn)
#pragma unroll
    for (int r = 0; r < 4; ++r) {
      int qq = q0 + qw + quad * 4 + r;
      int d = tn * 16 + lane16;
      Ctx[((size_t)(b * SEQ + qq)) * DMODEL + h * DHEAD + d] =
          f2bf(oacc[tn][r] * rl[r]);
    }
  if (lane16 == 0) {
#pragma unroll
    for (int r = 0; r < 4; ++r) {
      int qq = q0 + qw + quad * 4 + r;
      ((float2*)stats)[(size_t)hb * SEQ + qq] = make_float2(mrow[r], rl[r]);
    }
  }
}

// ======================= probs writer (pass B) =======================
// Fully parallel over (q-block, hb, k-block): recompute one 64x128 S
// tile, normalize with stats, stream f32 probs straight to d_out.
__global__ __launch_bounds__(256) void attn_probs(
    const u16* __restrict__ Qp, const u16* __restrict__ Kp,
    const u32* __restrict__ mbits, const float* __restrict__ stats,
    float* __restrict__ attnOut) {
  __shared__ __align__(16) u16 qL[8 * 64 * 8];    // 8 KB
  __shared__ __align__(16) u16 kL[8 * 128 * 8];   // 16 KB
  int tid = threadIdx.x;
  int hb = blockIdx.y;
  int h = hb >> 1, b = hb & 1;
  int q0 = blockIdx.x * 64;
  int kp0 = blockIdx.z * 128;
  int wave = tid >> 6, lane = tid & 63;
  int lane16 = lane & 15, quad = lane >> 4;
  int qw = wave * 16;
  const u16* Qbase = Qp + ((size_t)(b * SEQ + q0)) * DMODEL + h * DHEAD;
  const u16* Kbase = Kp + ((size_t)(b * SEQ + kp0)) * DMODEL + h * DHEAD;
  const u32* Mb = mbits + ((size_t)(b * SEQ + q0)) * (SEQ / 32) + (kp0 >> 5);
#pragma unroll
  for (int p = 0; p < 2; ++p) {
    int c = tid + p * 256;
    int row = c >> 3, kq = c & 7;
    *(uint4*)(qL + (((kq * 64 + row) ^ kq) * 8)) =
        *(const uint4*)(Qbase + (size_t)row * DMODEL + kq * 8);
  }
#pragma unroll
  for (int p = 0; p < 4; ++p) {
    int c = tid + p * 256;
    int row = c >> 3, dq = c & 7;
    *(uint4*)(kL + (((dq * 128 + row) ^ dq) * 8)) =
        *(const uint4*)(Kbase + (size_t)row * DMODEL + dq * 8);
  }
  // hoist stats + mask words (independent of LDS) ahead of MFMA
  float2 st[4];
  uint4 mw[4];
#pragma unroll
  for (int r = 0; r < 4; ++r) {
    int m = qw + quad * 4 + r;
    st[r] = ((const float2*)stats)[(size_t)hb * SEQ + q0 + m];
    mw[r] = *(const uint4*)(Mb + (size_t)m * (SEQ / 32));
  }
  __syncthreads();
  int mq = qw + lane16;
  bf16x8 a0 = *(const bf16x8*)(qL + (((quad * 64 + mq) ^ quad) * 8));
  bf16x8 a1 = *(const bf16x8*)(qL + ((((4 + quad) * 64 + mq) ^ (4 + quad)) * 8));
  f32x4 s[8] = {};
#pragma unroll
  for (int tn = 0; tn < 8; ++tn) {
    int rowk = tn * 16 + lane16;
    bf16x8 b0 = *(const bf16x8*)(kL + (((quad * 128 + rowk) ^ quad) * 8));
    bf16x8 b1 = *(const bf16x8*)(kL + ((((4 + quad) * 128 + rowk) ^ (4 + quad)) * 8));
    s[tn] = __builtin_amdgcn_mfma_f32_16x16x32_bf16(a0, b0, s[tn], 0, 0, 0);
    s[tn] = __builtin_amdgcn_mfma_f32_16x16x32_bf16(a1, b1, s[tn], 0, 0, 0);
  }
  const float scale = 1.0f / 64.0f;
#pragma unroll
  for (int r = 0; r < 4; ++r) {
    int m = qw + quad * 4 + r;
    u32 mwv[4] = {mw[r].x, mw[r].y, mw[r].z, mw[r].w};
    float* dst = attnOut + ((size_t)hb * SEQ + q0 + m) * SEQ + kp0 + lane16;
#pragma unroll
    for (int tn = 0; tn < 8; ++tn) {
      float x = s[tn][r] * scale;
      if (((mwv[tn >> 1] >> (((tn & 1) << 4) + lane16)) & 1u) == 0u) x = -1e9f;
      __builtin_nontemporal_store(__expf(x - st[r].x) * st[r].y, dst + tn * 16);
    }
  }
}

// ======================= host launch ================================
extern "C" void kernel_launch(void* const* d_in, const int* in_sizes, int n_in,
                              void* d_out, int out_size, void* d_ws,
                              size_t ws_size, hipStream_t stream) {
  const float* q = (const float*)d_in[0];
  const float* k = (const float*)d_in[1];
  const float* v = (const float*)d_in[2];
  const int* mask = (const int*)d_in[3];
  const float* Wq = (const float*)d_in[4];
  const float* bq = (const float*)d_in[5];
  const float* Wk = (const float*)d_in[6];
  const float* bk = (const float*)d_in[7];
  const float* Wv = (const float*)d_in[8];
  const float* bv = (const float*)d_in[9];
  const float* Wo = (const float*)d_in[10];
  const float* bo = (const float*)d_in[11];

  u16* ws = (u16*)d_ws;
  u16* wtq = ws + 0;                   // bf16 [512][512] each
  u16* wtk = ws + 262144;
  u16* wtv = ws + 524288;
  u16* wto = ws + 786432;
  u16* Xq  = ws + 1048576;             // bf16 [4096][512] each
  u16* Xk  = ws + 3145728;
  u16* Xv  = ws + 5242880;
  u16* Qp  = ws + 7340032;             // bf16 [4096][512] each
  u16* Kp  = ws + 9437184;
  u16* Vp  = ws + 11534336;
  u16* Vt  = ws + 13631488;            // bf16 [(b*8+h)*64+d][2048]
  u16* Ctx = ws + 15728640;            // bf16 [4096][512]
  float* stats = (float*)(ws + 17825792);          // f32x2 [16][2048] = 256 KB
  u32* mbits   = (u32*)(ws + 17956864);            // 1 bit/elem = 1 MB

  float* outp = (float*)d_out;                        // f32 [2][2048][512]
  float* attnp = outp + (size_t)BB * SEQ * DMODEL;    // f32 [16][2048][2048]

  prep<<<dim3(4352), 256, 0, stream>>>(Wq, Wk, Wv, Wo, wtq, wtk, wtv, wto,
                                       q, k, v, Xq, Xk, Xv, mask, mbits);
  qkv_gemm<<<dim3(32, 4, 3), 256, 0, stream>>>(Xq, Xk, Xv, wtq, wtk, wtv,
                                               bq, bk, bv, Qp, Kp, Vp);
  transpose_v<<<dim3(32, 16), 256, 0, stream>>>(Vp, Vt);
  attn_flash<<<dim3(32, 16), 256, 0, stream>>>(Qp, Kp, Vt, mbits, stats, Ctx);
  attn_probs<<<dim3(32, 16, 16), 256, 0, stream>>>(Qp, Kp, mbits, stats, attnp);
  out_gemm<<<dim3(32, 4), 256, 0, stream>>>(Ctx, wto, bo, q, outp);
}

// Round 3
// 469.766 us; speedup vs baseline: 1.1417x; 1.1417x over previous
//
#include <hip/hip_runtime.h>
#include <hip/hip_bf16.h>
#include <cstdint>
#include <cstddef>

// ---- problem constants ----
#define NH 8
#define DMODEL 512
#define DHEAD 64
#define BB 2
#define SEQ 2048

typedef __bf16 bf16x8 __attribute__((ext_vector_type(8)));
typedef float f32x4 __attribute__((ext_vector_type(4)));
typedef unsigned short u16;
typedef unsigned int u32;

__device__ __forceinline__ u16 f2bf(float f) {
  u32 x = __float_as_uint(f);
  x += 0x7fffu + ((x >> 16) & 1u);
  return (u16)(x >> 16);
}
__device__ __forceinline__ u32 pk2(float lo, float hi) {
  return (u32)f2bf(lo) | ((u32)f2bf(hi) << 16);
}

// global -> LDS direct DMA, 16 B per lane. LDS dest must be wave-uniform
// base (HW writes base + lane*16); global src is per-lane (pre-swizzled).
__device__ __forceinline__ void gl_lds16(const void* g, void* l) {
  __builtin_amdgcn_global_load_lds(
      (const __attribute__((address_space(1))) unsigned int*)g,
      (__attribute__((address_space(3))) unsigned int*)l, 16, 0, 0);
}

// ============ prep: W transposes + X f32->bf16 + mask bits ===========
// blockIdx.x ranges:
//   [0,256)        : transpose 4 weight matrices (64 tiles each)
//   [256,3328)     : convert q,k,v f32 -> bf16 (1024 blocks each)
//   [3328,4352)    : mask int32 -> bitmask (32 ints / thread)
__global__ __launch_bounds__(256) void prep(
    const float* Wq, const float* Wk, const float* Wv, const float* Wo,
    u16* wtq, u16* wtk, u16* wtv, u16* wto,
    const float* xq, const float* xk, const float* xv,
    u16* Xq, u16* Xk, u16* Xv,
    const int* __restrict__ mask, u32* __restrict__ mbits) {
  __shared__ u16 t[64][72];
  int bid = blockIdx.x, tid = threadIdx.x;
  if (bid < 256) {
    const float* srcs[4] = {Wq, Wk, Wv, Wo};
    u16* dsts[4] = {wtq, wtk, wtv, wto};
    int z = bid >> 6, tile = bid & 63;
    int r0 = (tile >> 3) * 64, c0 = (tile & 7) * 64;
    const float* src = srcs[z] + (size_t)r0 * DMODEL + c0;
    u16* dst = dsts[z] + (size_t)c0 * DMODEL + r0;
#pragma unroll
    for (int p = 0; p < 4; ++p) {
      int c = tid + p * 256;
      int row = c >> 4, cc = (c & 15) * 4;
      float4 f = *(const float4*)(src + (size_t)row * DMODEL + cc);
      t[row][cc + 0] = f2bf(f.x); t[row][cc + 1] = f2bf(f.y);
      t[row][cc + 2] = f2bf(f.z); t[row][cc + 3] = f2bf(f.w);
    }
    __syncthreads();
#pragma unroll
    for (int p = 0; p < 2; ++p) {
      int c = tid + p * 256;
      int n = c >> 3, kc = (c & 7) * 8;
      uint4 w;
      w.x = (u32)t[kc + 0][n] | ((u32)t[kc + 1][n] << 16);
      w.y = (u32)t[kc + 2][n] | ((u32)t[kc + 3][n] << 16);
      w.z = (u32)t[kc + 4][n] | ((u32)t[kc + 5][n] << 16);
      w.w = (u32)t[kc + 6][n] | ((u32)t[kc + 7][n] << 16);
      *(uint4*)(dst + (size_t)n * DMODEL + kc) = w;
    }
  } else if (bid < 3328) {
    int id = bid - 256;
    const float* src = (id < 1024) ? xq : (id < 2048) ? xk : xv;
    u16* dst = (id < 1024) ? Xq : (id < 2048) ? Xk : Xv;
    size_t off = (size_t)(id & 1023) * 2048 + (size_t)tid * 8;
    float4 f0 = *(const float4*)(src + off);
    float4 f1 = *(const float4*)(src + off + 4);
    uint4 w = make_uint4(pk2(f0.x, f0.y), pk2(f0.z, f0.w),
                         pk2(f1.x, f1.y), pk2(f1.z, f1.w));
    *(uint4*)(dst + off) = w;
  } else {
    size_t w0 = (size_t)(bid - 3328) * 256 + tid;   // output word index
    const int* mp = mask + w0 * 32;
    u32 bits = 0;
#pragma unroll
    for (int c = 0; c < 8; ++c) {
      uint4 v = *(const uint4*)(mp + c * 4);
      bits |= (v.x != 0 ? 1u : 0u) << (c * 4 + 0);
      bits |= (v.y != 0 ? 1u : 0u) << (c * 4 + 1);
      bits |= (v.z != 0 ? 1u : 0u) << (c * 4 + 2);
      bits |= (v.w != 0 ? 1u : 0u) << (c * 4 + 3);
    }
    mbits[w0] = bits;
  }
}

// ============ V' bf16 [B*L][512] -> Vt[(b*8+h)*64+d][L] ============
__global__ __launch_bounds__(256) void transpose_v(const u16* Vp, u16* Vt) {
  __shared__ u16 t[64][72];
  int hb2 = blockIdx.y;               // b*8 + h
  int b = hb2 >> 3, h = hb2 & 7;
  int kp0 = blockIdx.x * 64;
  const u16* src = Vp + ((size_t)(b * SEQ + kp0)) * DMODEL + h * DHEAD;
  u16* dst = Vt + ((size_t)hb2 * DHEAD) * SEQ + kp0;
  int tid = threadIdx.x;
#pragma unroll
  for (int p = 0; p < 2; ++p) {
    int c = tid + p * 256;
    int row = c >> 3, cc = (c & 7) * 8;
    uint4 w = *(const uint4*)(src + (size_t)row * DMODEL + cc);
    t[row][cc + 0] = (u16)(w.x);  t[row][cc + 1] = (u16)(w.x >> 16);
    t[row][cc + 2] = (u16)(w.y);  t[row][cc + 3] = (u16)(w.y >> 16);
    t[row][cc + 4] = (u16)(w.z);  t[row][cc + 5] = (u16)(w.z >> 16);
    t[row][cc + 6] = (u16)(w.w);  t[row][cc + 7] = (u16)(w.w >> 16);
  }
  __syncthreads();
#pragma unroll
  for (int p = 0; p < 2; ++p) {
    int c = tid + p * 256;
    int n = c >> 3, kc = (c & 7) * 8;
    uint4 w;
    w.x = (u32)t[kc + 0][n] | ((u32)t[kc + 1][n] << 16);
    w.y = (u32)t[kc + 2][n] | ((u32)t[kc + 3][n] << 16);
    w.z = (u32)t[kc + 4][n] | ((u32)t[kc + 5][n] << 16);
    w.w = (u32)t[kc + 6][n] | ((u32)t[kc + 7][n] << 16);
    *(uint4*)(dst + (size_t)n * SEQ + kc) = w;
  }
}

// ======================= 128xBN MFMA GEMM ==========================
// Y[4096][512] = X[4096][512] @ W[512][512] (+bias (+resid)), BN = TN*32.
// Staging via global_load_lds (linear LDS dest, swizzled global source):
// slot = row*4 + (kc ^ ((row>>1)&3))  -> fragment ds_read_b128 is 2-way
// (free) on banks; DMA writes have no LDS write phase at all.
template <int TN, bool YF32>
__device__ __forceinline__ void gemm_body(const u16* __restrict__ X,
                                          const u16* __restrict__ Wt,
                                          const float* __restrict__ bias,
                                          const float* __restrict__ resid,
                                          void* Yv) {
  __shared__ __align__(16) u16 aL[128 * 32];        // 8 KB, 512 slots
  __shared__ __align__(16) u16 bL[TN * 32 * 32];    // TN*128 slots
  int tid = threadIdx.x;
  int m0 = blockIdx.x * 128, n0 = blockIdx.y * (TN * 32);
  int wave = tid >> 6, lane = tid & 63;
  int lane16 = lane & 15, quad = lane >> 4;
  int wrow = (wave >> 1) * 64, wcol = (wave & 1) * (TN * 16);
  const u16* Abase = X + (size_t)m0 * DMODEL;
  const u16* Bbase = Wt + (size_t)n0 * DMODEL;
  f32x4 acc[4][TN] = {};
  for (int kt = 0; kt < 16; ++kt) {
    int k0 = kt * 32;
    __syncthreads();                 // prior-tile reads complete
#pragma unroll
    for (int p = 0; p < 2; ++p) {    // A: 512 slots
      int s = p * 256 + tid;
      int row = s >> 2, kc = (s & 3) ^ ((s >> 3) & 3);
      gl_lds16(Abase + (size_t)row * DMODEL + k0 + kc * 8,
               aL + (size_t)(p * 256 + wave * 64) * 8);
    }
#pragma unroll
    for (int p = 0; p < TN / 2; ++p) {  // B: TN*128 slots
      int s = p * 256 + tid;
      int row = s >> 2, kc = (s & 3) ^ ((s >> 3) & 3);
      gl_lds16(Bbase + (size_t)row * DMODEL + k0 + kc * 8,
               bL + (size_t)(p * 256 + wave * 64) * 8);
    }
    __syncthreads();                 // drains vmcnt -> tile visible
    bf16x8 aF[4], bF[TN];
#pragma unroll
    for (int t = 0; t < 4; ++t) {
      int r = wrow + t * 16 + lane16;
      aF[t] = *(const bf16x8*)(aL + (size_t)(r * 4 + (quad ^ ((r >> 1) & 3))) * 8);
    }
#pragma unroll
    for (int t = 0; t < TN; ++t) {
      int r = wcol + t * 16 + lane16;
      bF[t] = *(const bf16x8*)(bL + (size_t)(r * 4 + (quad ^ ((r >> 1) & 3))) * 8);
    }
#pragma unroll
    for (int tm = 0; tm < 4; ++tm)
#pragma unroll
      for (int tn = 0; tn < TN; ++tn)
        acc[tm][tn] = __builtin_amdgcn_mfma_f32_16x16x32_bf16(
            aF[tm], bF[tn], acc[tm][tn], 0, 0, 0);
  }
  // epilogue: C row = quad*4 + r, col = lane16 (m89/m91 verified layout)
#pragma unroll
  for (int tm = 0; tm < 4; ++tm) {
#pragma unroll
    for (int r = 0; r < 4; ++r) {
      int mm = m0 + wrow + tm * 16 + quad * 4 + r;
#pragma unroll
      for (int tn = 0; tn < TN; ++tn) {
        int n = n0 + wcol + tn * 16 + lane16;
        float v = acc[tm][tn][r] + bias[n];
        if (YF32) {
          ((float*)Yv)[(size_t)mm * DMODEL + n] = v + resid[(size_t)mm * DMODEL + n];
        } else {
          ((u16*)Yv)[(size_t)mm * DMODEL + n] = f2bf(v);
        }
      }
    }
  }
}

__global__ __launch_bounds__(256) void qkv_gemm(
    const u16* Xq, const u16* Xk, const u16* Xv,
    const u16* wtq, const u16* wtk, const u16* wtv,
    const float* bq, const float* bk, const float* bv,
    u16* yq, u16* yk, u16* yv) {
  int z = blockIdx.z;
  const u16* X = (z == 0) ? Xq : (z == 1) ? Xk : Xv;
  const u16* Wt = (z == 0) ? wtq : (z == 1) ? wtk : wtv;
  const float* bias = (z == 0) ? bq : (z == 1) ? bk : bv;
  u16* Y = (z == 0) ? yq : (z == 1) ? yk : yv;
  gemm_body<2, false>(X, Wt, bias, nullptr, Y);
}

__global__ __launch_bounds__(256) void out_gemm(const u16* X, const u16* Wt,
                                                const float* bias,
                                                const float* resid, float* Y) {
  gemm_body<2, true>(X, Wt, bias, resid, Y);
}

// ======================= flash attention (pass A) ====================
// One block = (b,h) x 64 Q rows. Online softmax + rescaled PV (r1 flow;
// T14 reverted). All staging via global_load_lds with swizzled sources:
//   K/Q: slot = row*8 + (dq ^ (row&7));  V: slot = d*16 + (kpq ^ (d&7)).
// Fragment reads are 2-way on banks (free); staging has no VALU phase.
__global__ __launch_bounds__(256) void attn_flash(
    const u16* __restrict__ Qp, const u16* __restrict__ Kp,
    const u16* __restrict__ Vt, const u32* __restrict__ mbits,
    float* __restrict__ stats, u16* __restrict__ Ctx) {
  __shared__ __align__(16) u16 kL[1024 * 8];   // 16 KB (Q -> K -> P)
  __shared__ __align__(16) u16 vL[1024 * 8];   // 16 KB
  int tid = threadIdx.x;
  int hb = blockIdx.y;             // h*B + b
  int h = hb >> 1, b = hb & 1;
  int q0 = blockIdx.x * 64;
  int wave = tid >> 6, lane = tid & 63;
  int lane16 = lane & 15, quad = lane >> 4;
  int qw = wave * 16;

  const u16* Qbase = Qp + ((size_t)(b * SEQ + q0)) * DMODEL + h * DHEAD;
  const u16* Kbase = Kp + ((size_t)b * SEQ) * DMODEL + h * DHEAD;
  const u16* Vbase = Vt + ((size_t)(b * 8 + h) * DHEAD) * SEQ;
  const u32* Mb = mbits + ((size_t)(b * SEQ + q0)) * (SEQ / 32);

  // stage Q via DMA; hoist fragments to registers
#pragma unroll
  for (int p = 0; p < 2; ++p) {
    int sl = p * 256 + tid;
    int row = sl >> 3, dq = (sl & 7) ^ (row & 7);
    gl_lds16(Qbase + (size_t)row * DMODEL + dq * 8,
             kL + (size_t)(p * 256 + wave * 64) * 8);
  }
  __syncthreads();
  int mq = qw + lane16;
  bf16x8 a0 = *(const bf16x8*)(kL + (size_t)(mq * 8 + (quad ^ (mq & 7))) * 8);
  bf16x8 a1 = *(const bf16x8*)(kL + (size_t)(mq * 8 + ((4 + quad) ^ (mq & 7))) * 8);

  float mrow[4], lrow[4];
#pragma unroll
  for (int r = 0; r < 4; ++r) { mrow[r] = -1e30f; lrow[r] = 0.f; }
  f32x4 oacc[4] = {};
  const float scale = 1.0f / 64.0f;   // reference temperature = d_k

  for (int j = 0; j < 16; ++j) {
    int kp0 = j * 128;
    __syncthreads();                  // P/PV reads of kL,vL complete
#pragma unroll
    for (int p = 0; p < 4; ++p) {     // K: 1024 slots, V: 1024 slots
      int sl = p * 256 + tid;
      int rowK = sl >> 3, dq = (sl & 7) ^ (rowK & 7);
      gl_lds16(Kbase + (size_t)(kp0 + rowK) * DMODEL + dq * 8,
               kL + (size_t)(p * 256 + wave * 64) * 8);
      int dV = sl >> 4, kpq = (sl & 15) ^ (dV & 7);
      gl_lds16(Vbase + (size_t)dV * SEQ + kp0 + kpq * 8,
               vL + (size_t)(p * 256 + wave * 64) * 8);
    }
    uint4 mw[4];
#pragma unroll
    for (int r = 0; r < 4; ++r)
      mw[r] = *(const uint4*)(Mb + (size_t)(qw + quad * 4 + r) * (SEQ / 32) + (kp0 >> 5));
    __syncthreads();                  // drain DMA -> K/V visible
    f32x4 sc[8] = {};
    __builtin_amdgcn_s_setprio(1);
#pragma unroll
    for (int tn = 0; tn < 8; ++tn) {
      int rowk = tn * 16 + lane16;
      bf16x8 b0 = *(const bf16x8*)(kL + (size_t)(rowk * 8 + (quad ^ (rowk & 7))) * 8);
      bf16x8 b1 = *(const bf16x8*)(kL + (size_t)(rowk * 8 + ((4 + quad) ^ (rowk & 7))) * 8);
      sc[tn] = __builtin_amdgcn_mfma_f32_16x16x32_bf16(a0, b0, sc[tn], 0, 0, 0);
      sc[tn] = __builtin_amdgcn_mfma_f32_16x16x32_bf16(a1, b1, sc[tn], 0, 0, 0);
    }
    __builtin_amdgcn_s_setprio(0);
    float pv[4][8], cf[4];
#pragma unroll
    for (int r = 0; r < 4; ++r) {
      u32 mwv[4] = {mw[r].x, mw[r].y, mw[r].z, mw[r].w};
      float vmax = -1e30f, sv[8];
#pragma unroll
      for (int tn = 0; tn < 8; ++tn) {
        float x = sc[tn][r] * scale;
        if (((mwv[tn >> 1] >> (((tn & 1) << 4) + lane16)) & 1u) == 0u) x = -1e9f;
        sv[tn] = x;
        vmax = fmaxf(vmax, x);
      }
#pragma unroll
      for (int o = 1; o < 16; o <<= 1) vmax = fmaxf(vmax, __shfl_xor(vmax, o));
      float nm = fmaxf(mrow[r], vmax);
      cf[r] = __expf(mrow[r] - nm);
      float se = 0.f;
#pragma unroll
      for (int tn = 0; tn < 8; ++tn) {
        float e = __expf(sv[tn] - nm);
        pv[r][tn] = e;
        se += e;
      }
#pragma unroll
      for (int o = 1; o < 16; o <<= 1) se += __shfl_xor(se, o);
      lrow[r] = lrow[r] * cf[r] + se;
      mrow[r] = nm;
    }
#pragma unroll
    for (int tn = 0; tn < 4; ++tn)
#pragma unroll
      for (int r = 0; r < 4; ++r) oacc[tn][r] *= cf[r];
    __syncthreads();                  // all waves done reading kL (S phase)
    // write P into kL's space; swizzle block ^ ((m>>2)&7) separates quads
#pragma unroll
    for (int r = 0; r < 4; ++r) {
      int m = qw + quad * 4 + r;
      int sw = (m >> 2) & 7;
#pragma unroll
      for (int tn = 0; tn < 8; ++tn) {
        int kpl = tn * 16 + lane16;
        kL[((((kpl >> 3) * 64 + m) ^ sw) * 8) + (kpl & 7)] = f2bf(pv[r][tn]);
      }
    }
    __syncthreads();
    __builtin_amdgcn_s_setprio(1);
#pragma unroll
    for (int ks = 0; ks < 4; ++ks) {
      int kpq = ks * 4 + quad;
      bf16x8 aF = *(const bf16x8*)(kL + (size_t)(((kpq * 64 + mq) ^ ((mq >> 2) & 7))) * 8);
#pragma unroll
      for (int tn = 0; tn < 4; ++tn) {
        int d = tn * 16 + lane16;
        bf16x8 bF = *(const bf16x8*)(vL + (size_t)(d * 16 + (kpq ^ (d & 7))) * 8);
        oacc[tn] = __builtin_amdgcn_mfma_f32_16x16x32_bf16(aF, bF, oacc[tn], 0, 0, 0);
      }
    }
    __builtin_amdgcn_s_setprio(0);
  }
  float rl[4];
#pragma unroll
  for (int r = 0; r < 4; ++r) rl[r] = 1.0f / lrow[r];
#pragma unroll
  for (int tn = 0; tn < 4; ++tn)
#pragma unroll
    for (int r = 0; r < 4; ++r) {
      int qq = q0 + qw + quad * 4 + r;
      int d = tn * 16 + lane16;
      Ctx[((size_t)(b * SEQ + qq)) * DMODEL + h * DHEAD + d] =
          f2bf(oacc[tn][r] * rl[r]);
    }
  if (lane16 == 0) {
#pragma unroll
    for (int r = 0; r < 4; ++r) {
      int qq = q0 + qw + quad * 4 + r;
      ((float2*)stats)[(size_t)hb * SEQ + qq] = make_float2(mrow[r], rl[r]);
    }
  }
}

// ======================= probs writer (pass B) =======================
// Fully parallel over (q-block, hb, k-block): recompute one 64x128 S
// tile, normalize with stats, stream f32 probs straight to d_out.
__global__ __launch_bounds__(256) void attn_probs(
    const u16* __restrict__ Qp, const u16* __restrict__ Kp,
    const u32* __restrict__ mbits, const float* __restrict__ stats,
    float* __restrict__ attnOut) {
  __shared__ __align__(16) u16 qL[512 * 8];    // 8 KB
  __shared__ __align__(16) u16 kL[1024 * 8];   // 16 KB
  int tid = threadIdx.x;
  int hb = blockIdx.y;
  int h = hb >> 1, b = hb & 1;
  int q0 = blockIdx.x * 64;
  int kp0 = blockIdx.z * 128;
  int wave = tid >> 6, lane = tid & 63;
  int lane16 = lane & 15, quad = lane >> 4;
  int qw = wave * 16;
  const u16* Qbase = Qp + ((size_t)(b * SEQ + q0)) * DMODEL + h * DHEAD;
  const u16* Kbase = Kp + ((size_t)(b * SEQ + kp0)) * DMODEL + h * DHEAD;
  const u32* Mb = mbits + ((size_t)(b * SEQ + q0)) * (SEQ / 32) + (kp0 >> 5);
#pragma unroll
  for (int p = 0; p < 2; ++p) {
    int sl = p * 256 + tid;
    int row = sl >> 3, dq = (sl & 7) ^ (row & 7);
    gl_lds16(Qbase + (size_t)row * DMODEL + dq * 8,
             qL + (size_t)(p * 256 + wave * 64) * 8);
  }
#pragma unroll
  for (int p = 0; p < 4; ++p) {
    int sl = p * 256 + tid;
    int row = sl >> 3, dq = (sl & 7) ^ (row & 7);
    gl_lds16(Kbase + (size_t)row * DMODEL + dq * 8,
             kL + (size_t)(p * 256 + wave * 64) * 8);
  }
  // hoist stats + mask words (independent of LDS) ahead of MFMA
  float2 st[4];
  uint4 mw[4];
#pragma unroll
  for (int r = 0; r < 4; ++r) {
    int m = qw + quad * 4 + r;
    st[r] = ((const float2*)stats)[(size_t)hb * SEQ + q0 + m];
    mw[r] = *(const uint4*)(Mb + (size_t)m * (SEQ / 32));
  }
  __syncthreads();
  int mq = qw + lane16;
  bf16x8 a0 = *(const bf16x8*)(qL + (size_t)(mq * 8 + (quad ^ (mq & 7))) * 8);
  bf16x8 a1 = *(const bf16x8*)(qL + (size_t)(mq * 8 + ((4 + quad) ^ (mq & 7))) * 8);
  f32x4 sc[8] = {};
#pragma unroll
  for (int tn = 0; tn < 8; ++tn) {
    int rowk = tn * 16 + lane16;
    bf16x8 b0 = *(const bf16x8*)(kL + (size_t)(rowk * 8 + (quad ^ (rowk & 7))) * 8);
    bf16x8 b1 = *(const bf16x8*)(kL + (size_t)(rowk * 8 + ((4 + quad) ^ (rowk & 7))) * 8);
    sc[tn] = __builtin_amdgcn_mfma_f32_16x16x32_bf16(a0, b0, sc[tn], 0, 0, 0);
    sc[tn] = __builtin_amdgcn_mfma_f32_16x16x32_bf16(a1, b1, sc[tn], 0, 0, 0);
  }
  const float scale = 1.0f / 64.0f;
#pragma unroll
  for (int r = 0; r < 4; ++r) {
    int m = qw + quad * 4 + r;
    u32 mwv[4] = {mw[r].x, mw[r].y, mw[r].z, mw[r].w};
    float* dst = attnOut + ((size_t)hb * SEQ + q0 + m) * SEQ + kp0 + lane16;
#pragma unroll
    for (int tn = 0; tn < 8; ++tn) {
      float x = sc[tn][r] * scale;
      if (((mwv[tn >> 1] >> (((tn & 1) << 4) + lane16)) & 1u) == 0u) x = -1e9f;
      __builtin_nontemporal_store(__expf(x - st[r].x) * st[r].y, dst + tn * 16);
    }
  }
}

// ======================= host launch ================================
extern "C" void kernel_launch(void* const* d_in, const int* in_sizes, int n_in,
                              void* d_out, int out_size, void* d_ws,
                              size_t ws_size, hipStream_t stream) {
  const float* q = (const float*)d_in[0];
  const float* k = (const float*)d_in[1];
  const float* v = (const float*)d_in[2];
  const int* mask = (const int*)d_in[3];
  const float* Wq = (const float*)d_in[4];
  const float* bq = (const float*)d_in[5];
  const float* Wk = (const float*)d_in[6];
  const float* bk = (const float*)d_in[7];
  const float* Wv = (const float*)d_in[8];
  const float* bv = (const float*)d_in[9];
  const float* Wo = (const float*)d_in[10];
  const float* bo = (const float*)d_in[11];

  u16* ws = (u16*)d_ws;
  u16* wtq = ws + 0;                   // bf16 [512][512] each
  u16* wtk = ws + 262144;
  u16* wtv = ws + 524288;
  u16* wto = ws + 786432;
  u16* Xq  = ws + 1048576;             // bf16 [4096][512] each
  u16* Xk  = ws + 3145728;
  u16* Xv  = ws + 5242880;
  u16* Qp  = ws + 7340032;             // bf16 [4096][512] each
  u16* Kp  = ws + 9437184;
  u16* Vp  = ws + 11534336;
  u16* Vt  = ws + 13631488;            // bf16 [(b*8+h)*64+d][2048]
  u16* Ctx = ws + 15728640;            // bf16 [4096][512]
  float* stats = (float*)(ws + 17825792);          // f32x2 [16][2048] = 256 KB
  u32* mbits   = (u32*)(ws + 17956864);            // 1 bit/elem = 1 MB

  float* outp = (float*)d_out;                        // f32 [2][2048][512]
  float* attnp = outp + (size_t)BB * SEQ * DMODEL;    // f32 [16][2048][2048]

  prep<<<dim3(4352), 256, 0, stream>>>(Wq, Wk, Wv, Wo, wtq, wtk, wtv, wto,
                                       q, k, v, Xq, Xk, Xv, mask, mbits);
  qkv_gemm<<<dim3(32, 8, 3), 256, 0, stream>>>(Xq, Xk, Xv, wtq, wtk, wtv,
                                               bq, bk, bv, Qp, Kp, Vp);
  transpose_v<<<dim3(32, 16), 256, 0, stream>>>(Vp, Vt);
  attn_flash<<<dim3(32, 16), 256, 0, stream>>>(Qp, Kp, Vt, mbits, stats, Ctx);
  attn_probs<<<dim3(32, 16, 16), 256, 0, stream>>>(Qp, Kp, mbits, stats, attnp);
  out_gemm<<<dim3(32, 8), 256, 0, stream>>>(Ctx, wto, bo, q, outp);
}